// Round 7
// baseline (552.342 us; speedup 1.0000x reference)
//
#include <hip/hip_runtime.h>
#include <math.h>

#define BB 16
#define NN 512
#define HH 8
#define EE 128
#define HE 1024
#define QSCALE 0.08838834764831845f
#define NEGV -1000000000.0f

typedef short bf16x8 __attribute__((ext_vector_type(8)));
typedef float f32x4 __attribute__((ext_vector_type(4)));
typedef unsigned u32x4 __attribute__((ext_vector_type(4)));

// round-to-nearest-even fp32 -> bf16 pair (hi + lo residual). v ~= hi + lo to ~2^-17 rel.
__device__ __forceinline__ void split2(float v, unsigned short &hi, unsigned short &lo) {
    union { float f; unsigned u; } a; a.f = v;
    const unsigned r = (a.u + 0x7FFFu + ((a.u >> 16) & 1u)) >> 16;
    hi = (unsigned short)r;
    union { unsigned u; float f; } hf; hf.u = r << 16;
    const float res = v - hf.f;
    union { float f; unsigned u; } c; c.f = res;
    const unsigned r2 = (c.u + 0x7FFFu + ((c.u >> 16) & 1u)) >> 16;
    lo = (unsigned short)r2;
}

// ---------------------------------------------------------------------------
// k_split: x[1048576] -> xhi/xlo; Wq|Wk|Wv (3x131072) -> wchi/wclo [3072][128]
// ---------------------------------------------------------------------------
__global__ __launch_bounds__(256) void k_split(
    const float* __restrict__ x,
    const float* __restrict__ Wq, const float* __restrict__ Wk, const float* __restrict__ Wv,
    unsigned short* __restrict__ xhi, unsigned short* __restrict__ xlo,
    unsigned short* __restrict__ wchi, unsigned short* __restrict__ wclo)
{
    const int id = blockIdx.x * 256 + threadIdx.x;
    const int i4 = id * 4;
    const float* src;
    unsigned short *dh, *dl;
    int off;
    if (i4 < 1048576) { src = x; off = i4; dh = xhi + i4; dl = xlo + i4; }
    else {
        const int j = i4 - 1048576;
        const int msel = j >> 17;
        off = j & 131071;
        src = (msel == 0) ? Wq : (msel == 1) ? Wk : Wv;
        dh = wchi + j; dl = wclo + j;
    }
    const float4 v = *reinterpret_cast<const float4*>(src + off);
    unsigned short h[4], l[4];
    split2(v.x, h[0], l[0]); split2(v.y, h[1], l[1]);
    split2(v.z, h[2], l[2]); split2(v.w, h[3], l[3]);
    *reinterpret_cast<ushort4*>(dh) = *reinterpret_cast<ushort4*>(h);
    *reinterpret_cast<ushort4*>(dl) = *reinterpret_cast<ushort4*>(l);
}

// k_split_wo: Wo [128][1024] fp32 -> wohi/wolo (runs after k_attn, into dead QKV region)
__global__ __launch_bounds__(256) void k_split_wo(
    const float* __restrict__ Wo,
    unsigned short* __restrict__ wohi, unsigned short* __restrict__ wolo)
{
    const int i4 = (blockIdx.x * 256 + threadIdx.x) * 4;
    const float4 v = *reinterpret_cast<const float4*>(Wo + i4);
    unsigned short h[4], l[4];
    split2(v.x, h[0], l[0]); split2(v.y, h[1], l[1]);
    split2(v.z, h[2], l[2]); split2(v.w, h[3], l[3]);
    *reinterpret_cast<ushort4*>(wohi + i4) = *reinterpret_cast<ushort4*>(h);
    *reinterpret_cast<ushort4*>(wolo + i4) = *reinterpret_cast<ushort4*>(l);
}

// ---------------------------------------------------------------------------
// k_qkv: 3-term split-bf16 MFMA GEMM, LDS-free. M=8192, C=3072, K=128.
// Q/K tiles: operands SWAPPED (A=W, B=x) so D=[e][n] -> coalesced ushort4
// stores along e. V tiles: original order (D=[n][e]) -> ushort4 along n.
// ---------------------------------------------------------------------------
__global__ __launch_bounds__(256, 3) void k_qkv(
    const unsigned short* __restrict__ xhi, const unsigned short* __restrict__ xlo,
    const unsigned short* __restrict__ wchi, const unsigned short* __restrict__ wclo,
    const float* __restrict__ bq, const float* __restrict__ bk, const float* __restrict__ bv,
    unsigned short* __restrict__ Qhi, unsigned short* __restrict__ Qlo,
    unsigned short* __restrict__ Khi, unsigned short* __restrict__ Klo,
    unsigned short* __restrict__ VThi, unsigned short* __restrict__ VTlo)
{
    const int tid = threadIdx.x;
    const int w = tid >> 6, l = tid & 63, g = l >> 4, ln = l & 15;
    const int wm = w >> 1, wc = w & 1;
    const int m0  = blockIdx.x * 128;
    const int c0g = blockIdx.y * 128;
    const int wsel = c0g >> 10;
    const int cc0  = c0g & 1023;
    const float* __restrict__ bias = (wsel == 0) ? bq : (wsel == 1) ? bk : bv;

    f32x4 acc[4][4];
    const f32x4 fz = {0.f, 0.f, 0.f, 0.f};
    #pragma unroll
    for (int i = 0; i < 4; ++i)
        #pragma unroll
        for (int j = 0; j < 4; ++j) acc[i][j] = fz;

    #pragma unroll
    for (int ks = 0; ks < 4; ++ks) {
        bf16x8 ah[4], al[4], bh[4], bl[4];
        #pragma unroll
        for (int i = 0; i < 4; ++i) {
            const size_t a = (size_t)(m0 + wm * 64 + i * 16 + ln) * EE + ks * 32 + g * 8;
            ah[i] = *reinterpret_cast<const bf16x8*>(xhi + a);
            al[i] = *reinterpret_cast<const bf16x8*>(xlo + a);
        }
        #pragma unroll
        for (int j = 0; j < 4; ++j) {
            const size_t a = (size_t)(c0g + wc * 64 + j * 16 + ln) * EE + ks * 32 + g * 8;
            bh[j] = *reinterpret_cast<const bf16x8*>(wchi + a);
            bl[j] = *reinterpret_cast<const bf16x8*>(wclo + a);
        }
        if (wsel < 2) {
            // acc[j][i] = W-tile x x-tile: D rows = e, cols = n
            #pragma unroll
            for (int j = 0; j < 4; ++j)
                #pragma unroll
                for (int i = 0; i < 4; ++i) {
                    acc[j][i] = __builtin_amdgcn_mfma_f32_16x16x32_bf16(bh[j], al[i], acc[j][i], 0, 0, 0);
                    acc[j][i] = __builtin_amdgcn_mfma_f32_16x16x32_bf16(bl[j], ah[i], acc[j][i], 0, 0, 0);
                    acc[j][i] = __builtin_amdgcn_mfma_f32_16x16x32_bf16(bh[j], ah[i], acc[j][i], 0, 0, 0);
                }
        } else {
            #pragma unroll
            for (int i = 0; i < 4; ++i)
                #pragma unroll
                for (int j = 0; j < 4; ++j) {
                    acc[i][j] = __builtin_amdgcn_mfma_f32_16x16x32_bf16(ah[i], bl[j], acc[i][j], 0, 0, 0);
                    acc[i][j] = __builtin_amdgcn_mfma_f32_16x16x32_bf16(al[i], bh[j], acc[i][j], 0, 0, 0);
                    acc[i][j] = __builtin_amdgcn_mfma_f32_16x16x32_bf16(ah[i], bh[j], acc[i][j], 0, 0, 0);
                }
        }
    }

    const int b  = m0 >> 9;
    const int h  = cc0 >> 7;
    const int bh_ = b * HH + h;
    const int nb = (m0 & (NN - 1));

    if (wsel < 2) {
        unsigned short* __restrict__ hp = (wsel == 0) ? Qhi : Khi;
        unsigned short* __restrict__ lp = (wsel == 0) ? Qlo : Klo;
        #pragma unroll
        for (int j = 0; j < 4; ++j) {
            const int e0 = wc * 64 + j * 16 + g * 4;
            const float4 b4 = *reinterpret_cast<const float4*>(bias + cc0 + e0);
            const float bb4[4] = {b4.x, b4.y, b4.z, b4.w};
            #pragma unroll
            for (int i = 0; i < 4; ++i) {
                const int n = nb + wm * 64 + i * 16 + ln;
                unsigned short th[4], tl[4];
                #pragma unroll
                for (int r = 0; r < 4; ++r) split2(acc[j][i][r] + bb4[r], th[r], tl[r]);
                const size_t o = ((size_t)bh_ * NN + n) * EE + e0;
                *reinterpret_cast<ushort4*>(hp + o) = *reinterpret_cast<ushort4*>(th);
                *reinterpret_cast<ushort4*>(lp + o) = *reinterpret_cast<ushort4*>(tl);
            }
        }
    } else {
        #pragma unroll
        for (int j = 0; j < 4; ++j) {
            const int e = wc * 64 + j * 16 + ln;
            const float bj = bias[cc0 + e];
            #pragma unroll
            for (int i = 0; i < 4; ++i) {
                const int n = nb + wm * 64 + i * 16 + g * 4;
                unsigned short th[4], tl[4];
                #pragma unroll
                for (int r = 0; r < 4; ++r) split2(acc[i][j][r] + bj, th[r], tl[r]);
                const size_t o = ((size_t)bh_ * EE + e) * NN + n;
                *reinterpret_cast<ushort4*>(VThi + o) = *reinterpret_cast<ushort4*>(th);
                *reinterpret_cast<ushort4*>(VTlo + o) = *reinterpret_cast<ushort4*>(tl);
            }
        }
    }
}

// ---------------------------------------------------------------------------
// k_attn R7: no K/V staging at all - MFMA fragments load directly from global
// (contiguous 16B, L2/L1-hot). LDS = P only (16 KB) + 64-float l-xpose.
// QBLK=64, grid 1024 blocks -> 4 blocks/CU. 2 barriers/tile.
// PV operands swapped (A=V, B=P): D=[e][q] -> ushort4 Y stores along e.
// ---------------------------------------------------------------------------
__global__ __launch_bounds__(256, 2) void k_attn(
    const unsigned short* __restrict__ Qhi, const unsigned short* __restrict__ Qlo,
    const unsigned short* __restrict__ Khi_g, const unsigned short* __restrict__ Klo_g,
    const unsigned short* __restrict__ VThi_g, const unsigned short* __restrict__ VTlo_g,
    const float* __restrict__ dist, const float* __restrict__ mask,
    unsigned short* __restrict__ Yhi, unsigned short* __restrict__ Ylo)
{
    __shared__ __align__(16) unsigned sP[64 * 64];   // [q 64][k 64] u32(hi<<16|lo), swz
    __shared__ float sL[64];                         // per-q row-sum transpose

    const int tid = threadIdx.x;
    const int w  = tid >> 6;
    const int l  = tid & 63;
    const int g  = l >> 4;
    const int ln = l & 15;
    const int b  = blockIdx.x;       // lin%8 = b%8 -> whole batch on one XCD
    const int qb = blockIdx.y;
    const int h  = blockIdx.z;
    const int q0 = qb * 64;
    const int bh = b * HH + h;
    const size_t baseQ = (size_t)bh * NN * EE;
    const size_t baseV = (size_t)bh * EE * NN;

    // Q fragments (A-frag rows = q = w*16+ln)
    bf16x8 qa_hi[4], qa_lo[4];
    #pragma unroll
    for (int ks = 0; ks < 4; ++ks) {
        const size_t qoff = baseQ + (size_t)(q0 + w * 16 + ln) * EE + ks * 32 + g * 8;
        qa_hi[ks] = *reinterpret_cast<const bf16x8*>(Qhi + qoff);
        qa_lo[ks] = *reinterpret_cast<const bf16x8*>(Qlo + qoff);
    }

    float mq[4];
    #pragma unroll
    for (int r = 0; r < 4; ++r) mq[r] = mask[b * NN + q0 + w * 16 + g * 4 + r];

    float lrun[4] = {0.f, 0.f, 0.f, 0.f};
    f32x4 yacc[8];
    const f32x4 fz = {0.f, 0.f, 0.f, 0.f};
    #pragma unroll
    for (int et = 0; et < 8; ++et) yacc[et] = fz;

    for (int kt = 0; kt < 8; ++kt) {
        const int k0 = kt * 64;

        // ---- S = Q.K^T (3-term split); K frags direct from global ----
        f32x4 sacc[4];
        #pragma unroll
        for (int t = 0; t < 4; ++t) sacc[t] = fz;

        #pragma unroll
        for (int ks = 0; ks < 4; ++ks) {
            #pragma unroll
            for (int t = 0; t < 4; ++t) {
                const size_t ko = baseQ + (size_t)(k0 + t * 16 + ln) * EE + ks * 32 + g * 8;
                const bf16x8 kbh = *reinterpret_cast<const bf16x8*>(Khi_g + ko);
                const bf16x8 kbl = *reinterpret_cast<const bf16x8*>(Klo_g + ko);
                sacc[t] = __builtin_amdgcn_mfma_f32_16x16x32_bf16(qa_hi[ks], kbh, sacc[t], 0, 0, 0);
                sacc[t] = __builtin_amdgcn_mfma_f32_16x16x32_bf16(qa_lo[ks], kbh, sacc[t], 0, 0, 0);
                sacc[t] = __builtin_amdgcn_mfma_f32_16x16x32_bf16(qa_hi[ks], kbl, sacc[t], 0, 0, 0);
            }
        }

        // dist + k-mask for this tile
        float mk[4];
        #pragma unroll
        for (int t = 0; t < 4; ++t) mk[t] = mask[b * NN + k0 + t * 16 + ln];
        float dv[4][4];
        #pragma unroll
        for (int r = 0; r < 4; ++r) {
            const size_t drow = ((size_t)b * NN + q0 + w * 16 + g * 4 + r) * NN + k0;
            #pragma unroll
            for (int t = 0; t < 4; ++t) dv[t][r] = dist[drow + t * 16 + ln];
        }

        // ---- no-max softmax: p = exp(s); write split-packed P to LDS ----
        #pragma unroll
        for (int r = 0; r < 4; ++r) {
            float p[4], ls = 0.f;
            #pragma unroll
            for (int t = 0; t < 4; ++t) {
                const bool live = (mq[r] != 0.f) && (mk[t] != 0.f);
                const float sv = live ? fmaf(sacc[t][r], QSCALE, dv[t][r]) : NEGV;
                p[t] = __expf(sv);              // exp(-1e9) == 0 exactly
                ls += p[t];
            }
            lrun[r] += ls;
            const int q = w * 16 + g * 4 + r;
            #pragma unroll
            for (int t = 0; t < 4; ++t) {
                unsigned short ph, pl;
                split2(p[t], ph, pl);
                const int k = t * 16 + ln;
                const int off = q * 256 + ((k * 4) ^ ((q & 7) << 4));
                *reinterpret_cast<unsigned*>((char*)sP + off) = ((unsigned)ph << 16) | pl;
            }
        }
        __syncthreads();   // P visible

        // ---- Y += V.P (operands swapped: D rows = e, cols = q) ----
        #pragma unroll
        for (int ks = 0; ks < 2; ++ks) {
            // P B-frag: q = w*16+ln, k = ks*32+g*8 .. +7 (8 packed u32 = 2 uint4)
            const int q = w * 16 + ln;
            const int swz = (q & 7) << 4;
            const int colb = ks * 128 + g * 32;
            const uint4 r0 = *reinterpret_cast<const uint4*>((char*)sP + q * 256 + (colb ^ swz));
            const uint4 r1 = *reinterpret_cast<const uint4*>((char*)sP + q * 256 + ((colb + 16) ^ swz));
            const unsigned wrd[8] = {r0.x, r0.y, r0.z, r0.w, r1.x, r1.y, r1.z, r1.w};
            unsigned hh[4], llw[4];
            #pragma unroll
            for (int d = 0; d < 4; ++d) {
                hh[d]  = __builtin_amdgcn_perm(wrd[2 * d + 1], wrd[2 * d], 0x07060302u);
                llw[d] = __builtin_amdgcn_perm(wrd[2 * d + 1], wrd[2 * d], 0x05040100u);
            }
            u32x4 th = {hh[0], hh[1], hh[2], hh[3]};
            u32x4 tl = {llw[0], llw[1], llw[2], llw[3]};
            const bf16x8 pah = __builtin_bit_cast(bf16x8, th);
            const bf16x8 pal = __builtin_bit_cast(bf16x8, tl);

            #pragma unroll
            for (int et = 0; et < 8; ++et) {
                const size_t vo = baseV + (size_t)(et * 16 + ln) * NN + k0 + ks * 32 + g * 8;
                const bf16x8 vbh = *reinterpret_cast<const bf16x8*>(VThi_g + vo);
                const bf16x8 vbl = *reinterpret_cast<const bf16x8*>(VTlo_g + vo);
                yacc[et] = __builtin_amdgcn_mfma_f32_16x16x32_bf16(vbh, pal, yacc[et], 0, 0, 0);
                yacc[et] = __builtin_amdgcn_mfma_f32_16x16x32_bf16(vbl, pah, yacc[et], 0, 0, 0);
                yacc[et] = __builtin_amdgcn_mfma_f32_16x16x32_bf16(vbh, pah, yacc[et], 0, 0, 0);
            }
        }
        __syncthreads();   // P free for next tile
    }

    // ---- row-sum reduce + transpose l to q=ln via LDS ----
    #pragma unroll
    for (int r = 0; r < 4; ++r) {
        float ls = lrun[r];
        ls += __shfl_xor(ls, 1);
        ls += __shfl_xor(ls, 2);
        ls += __shfl_xor(ls, 4);
        ls += __shfl_xor(ls, 8);
        sL[w * 16 + g * 4 + r] = ls;     // all 16 ln-lanes write same value
    }
    __syncthreads();
    const float linv = 1.0f / fmaxf(sL[w * 16 + ln], 1e-30f);

    // ---- epilogue: yacc rows = e (4 consecutive), col q = ln -> ushort4 ----
    const int q = q0 + w * 16 + ln;
    #pragma unroll
    for (int et = 0; et < 8; ++et) {
        unsigned short th[4], tl[4];
        #pragma unroll
        for (int r = 0; r < 4; ++r) split2(yacc[et][r] * linv, th[r], tl[r]);
        const size_t o = ((size_t)(b * NN + q)) * HE + h * EE + et * 16 + g * 4;
        *reinterpret_cast<ushort4*>(Yhi + o) = *reinterpret_cast<ushort4*>(th);
        *reinterpret_cast<ushort4*>(Ylo + o) = *reinterpret_cast<ushort4*>(tl);
    }
}

// ---------------------------------------------------------------------------
// k_out: 3-term split MFMA, operands swapped (A=Wo, B=Y): D=[c][m] ->
// float4 stores along c. M=8192, C=128, K=1024. m-tile 16, 512 blocks.
// ---------------------------------------------------------------------------
__global__ __launch_bounds__(256) void k_out(
    const unsigned short* __restrict__ Yhi, const unsigned short* __restrict__ Ylo,
    const unsigned short* __restrict__ wohi, const unsigned short* __restrict__ wolo,
    const float* __restrict__ bo, const float* __restrict__ mask,
    float* __restrict__ out)
{
    const int tid = threadIdx.x;
    const int w = tid >> 6, l = tid & 63, g = l >> 4, ln = l & 15;
    const int m0 = blockIdx.x * 16;
    const int cq = w * 32;

    f32x4 acc[2];
    const f32x4 fz = {0.f, 0.f, 0.f, 0.f};
    acc[0] = fz; acc[1] = fz;

    #pragma unroll 4
    for (int ks = 0; ks < 32; ++ks) {
        const size_t a = (size_t)(m0 + ln) * HE + ks * 32 + g * 8;
        const bf16x8 ah = *reinterpret_cast<const bf16x8*>(Yhi + a);
        const bf16x8 al = *reinterpret_cast<const bf16x8*>(Ylo + a);
        #pragma unroll
        for (int jc = 0; jc < 2; ++jc) {
            const size_t bo_ = (size_t)(cq + jc * 16 + ln) * HE + ks * 32 + g * 8;
            const bf16x8 bh = *reinterpret_cast<const bf16x8*>(wohi + bo_);
            const bf16x8 bl = *reinterpret_cast<const bf16x8*>(wolo + bo_);
            acc[jc] = __builtin_amdgcn_mfma_f32_16x16x32_bf16(bh, al, acc[jc], 0, 0, 0);
            acc[jc] = __builtin_amdgcn_mfma_f32_16x16x32_bf16(bl, ah, acc[jc], 0, 0, 0);
            acc[jc] = __builtin_amdgcn_mfma_f32_16x16x32_bf16(bh, ah, acc[jc], 0, 0, 0);
        }
    }

    const int m = m0 + ln;
    const int b = m >> 9, n = m & (NN - 1);
    const float mm = mask[b * NN + n];
    #pragma unroll
    for (int jc = 0; jc < 2; ++jc) {
        const int c0 = cq + jc * 16 + g * 4;
        const float4 b4 = *reinterpret_cast<const float4*>(bo + c0);
        float4 o;
        o.x = (acc[jc][0] + b4.x) * mm;
        o.y = (acc[jc][1] + b4.y) * mm;
        o.z = (acc[jc][2] + b4.z) * mm;
        o.w = (acc[jc][3] + b4.w) * mm;
        *reinterpret_cast<float4*>(out + (size_t)m * EE + c0) = o;
    }
}

// ---------------------------------------------------------------------------
extern "C" void kernel_launch(void* const* d_in, const int* in_sizes, int n_in,
                              void* d_out, int out_size, void* d_ws, size_t ws_size,
                              hipStream_t stream) {
    const float* x    = (const float*)d_in[0];
    const float* dist = (const float*)d_in[1];
    const float* mask = (const float*)d_in[2];
    const float* Wq   = (const float*)d_in[3];
    const float* bq   = (const float*)d_in[4];
    const float* Wk   = (const float*)d_in[5];
    const float* bk   = (const float*)d_in[6];
    const float* Wv   = (const float*)d_in[7];
    const float* bv   = (const float*)d_in[8];
    const float* Wo   = (const float*)d_in[9];
    const float* bo   = (const float*)d_in[10];
    float* out = (float*)d_out;

    const size_t SZ = (size_t)BB * HH * NN * EE;     // 8,388,608 elems
    if (ws_size < SZ * 16) return;                   // 134,217,728 B
    char* ws = (char*)d_ws;
    unsigned short* Qhi  = (unsigned short*)(ws);
    unsigned short* Qlo  = (unsigned short*)(ws + 1 * 16777216);
    unsigned short* Khi  = (unsigned short*)(ws + 2 * 16777216);
    unsigned short* Klo  = (unsigned short*)(ws + 3 * 16777216);
    unsigned short* VThi = (unsigned short*)(ws + 4 * 16777216);
    unsigned short* VTlo = (unsigned short*)(ws + 5 * 16777216);
    char* yreg = ws + 6 * 16777216;
    unsigned short* Yhi  = (unsigned short*)(yreg);
    unsigned short* Ylo  = (unsigned short*)(yreg + 16777216);
    unsigned short* xhi  = (unsigned short*)(yreg);
    unsigned short* xlo  = (unsigned short*)(yreg + 2097152);
    unsigned short* wchi = (unsigned short*)(yreg + 4194304);
    unsigned short* wclo = (unsigned short*)(yreg + 4980736);
    unsigned short* wohi = (unsigned short*)(ws);
    unsigned short* wolo = (unsigned short*)(ws + 262144);

    k_split<<<1408, 256, 0, stream>>>(x, Wq, Wk, Wv, xhi, xlo, wchi, wclo);
    k_qkv<<<dim3(64, 24), 256, 0, stream>>>(xhi, xlo, wchi, wclo, bq, bk, bv,
                                            Qhi, Qlo, Khi, Klo, VThi, VTlo);
    k_attn<<<dim3(BB, NN / 64, HH), 256, 0, stream>>>(Qhi, Qlo, Khi, Klo, VThi, VTlo,
                                                      dist, mask, Yhi, Ylo);
    k_split_wo<<<128, 256, 0, stream>>>(Wo, wohi, wolo);
    k_out<<<512, 256, 0, stream>>>(Yhi, Ylo, wohi, wolo, bo, mask, out);
}

// Round 8
// 320.183 us; speedup vs baseline: 1.7251x; 1.7251x over previous
//
#include <hip/hip_runtime.h>
#include <math.h>

#define BB 16
#define NN 512
#define HH 8
#define EE 128
#define HE 1024
#define QSCALE 0.08838834764831845f
#define NEGV -1000000000.0f

typedef short bf16x8 __attribute__((ext_vector_type(8)));
typedef float f32x4 __attribute__((ext_vector_type(4)));
typedef unsigned u32x4 __attribute__((ext_vector_type(4)));

// round-to-nearest-even fp32 -> bf16 pair (hi + lo residual). v ~= hi + lo to ~2^-17 rel.
__device__ __forceinline__ void split2(float v, unsigned short &hi, unsigned short &lo) {
    union { float f; unsigned u; } a; a.f = v;
    const unsigned r = (a.u + 0x7FFFu + ((a.u >> 16) & 1u)) >> 16;
    hi = (unsigned short)r;
    union { unsigned u; float f; } hf; hf.u = r << 16;
    const float res = v - hf.f;
    union { float f; unsigned u; } c; c.f = res;
    const unsigned r2 = (c.u + 0x7FFFu + ((c.u >> 16) & 1u)) >> 16;
    lo = (unsigned short)r2;
}

// direct global->LDS 16B/lane (no VGPR round-trip)
__device__ __forceinline__ void gload16(const void* g, void* l) {
    __builtin_amdgcn_global_load_lds(
        (const __attribute__((address_space(1))) unsigned*)g,
        (__attribute__((address_space(3))) unsigned*)l, 16, 0, 0);
}

// ---------------------------------------------------------------------------
// k_split: x[1048576] -> xhi/xlo; Wq|Wk|Wv (3x131072) -> wchi/wclo [3072][128]
// ---------------------------------------------------------------------------
__global__ __launch_bounds__(256) void k_split(
    const float* __restrict__ x,
    const float* __restrict__ Wq, const float* __restrict__ Wk, const float* __restrict__ Wv,
    unsigned short* __restrict__ xhi, unsigned short* __restrict__ xlo,
    unsigned short* __restrict__ wchi, unsigned short* __restrict__ wclo)
{
    const int id = blockIdx.x * 256 + threadIdx.x;
    const int i4 = id * 4;
    const float* src;
    unsigned short *dh, *dl;
    int off;
    if (i4 < 1048576) { src = x; off = i4; dh = xhi + i4; dl = xlo + i4; }
    else {
        const int j = i4 - 1048576;
        const int msel = j >> 17;
        off = j & 131071;
        src = (msel == 0) ? Wq : (msel == 1) ? Wk : Wv;
        dh = wchi + j; dl = wclo + j;
    }
    const float4 v = *reinterpret_cast<const float4*>(src + off);
    unsigned short h[4], l[4];
    split2(v.x, h[0], l[0]); split2(v.y, h[1], l[1]);
    split2(v.z, h[2], l[2]); split2(v.w, h[3], l[3]);
    *reinterpret_cast<ushort4*>(dh) = *reinterpret_cast<ushort4*>(h);
    *reinterpret_cast<ushort4*>(dl) = *reinterpret_cast<ushort4*>(l);
}

// k_split_wo: Wo [128][1024] fp32 -> wohi/wolo
__global__ __launch_bounds__(256) void k_split_wo(
    const float* __restrict__ Wo,
    unsigned short* __restrict__ wohi, unsigned short* __restrict__ wolo)
{
    const int i4 = (blockIdx.x * 256 + threadIdx.x) * 4;
    const float4 v = *reinterpret_cast<const float4*>(Wo + i4);
    unsigned short h[4], l[4];
    split2(v.x, h[0], l[0]); split2(v.y, h[1], l[1]);
    split2(v.z, h[2], l[2]); split2(v.w, h[3], l[3]);
    *reinterpret_cast<ushort4*>(wohi + i4) = *reinterpret_cast<ushort4*>(h);
    *reinterpret_cast<ushort4*>(wolo + i4) = *reinterpret_cast<ushort4*>(l);
}

// ---------------------------------------------------------------------------
// k_qkv: 3-term split-bf16 MFMA GEMM, LDS-free (R7-verified). M=8192, C=3072.
// Q/K: swapped operands -> D=[e][n], coalesced ushort4 epilogue along e.
// V: D=[n][e] -> ushort4 along n into [bh][e][n].
// ---------------------------------------------------------------------------
__global__ __launch_bounds__(256, 3) void k_qkv(
    const unsigned short* __restrict__ xhi, const unsigned short* __restrict__ xlo,
    const unsigned short* __restrict__ wchi, const unsigned short* __restrict__ wclo,
    const float* __restrict__ bq, const float* __restrict__ bk, const float* __restrict__ bv,
    unsigned short* __restrict__ Qhi, unsigned short* __restrict__ Qlo,
    unsigned short* __restrict__ Khi, unsigned short* __restrict__ Klo,
    unsigned short* __restrict__ VThi, unsigned short* __restrict__ VTlo)
{
    const int tid = threadIdx.x;
    const int w = tid >> 6, l = tid & 63, g = l >> 4, ln = l & 15;
    const int wm = w >> 1, wc = w & 1;
    const int m0  = blockIdx.x * 128;
    const int c0g = blockIdx.y * 128;
    const int wsel = c0g >> 10;
    const int cc0  = c0g & 1023;
    const float* __restrict__ bias = (wsel == 0) ? bq : (wsel == 1) ? bk : bv;

    f32x4 acc[4][4];
    const f32x4 fz = {0.f, 0.f, 0.f, 0.f};
    #pragma unroll
    for (int i = 0; i < 4; ++i)
        #pragma unroll
        for (int j = 0; j < 4; ++j) acc[i][j] = fz;

    #pragma unroll
    for (int ks = 0; ks < 4; ++ks) {
        bf16x8 ah[4], al[4], bh[4], bl[4];
        #pragma unroll
        for (int i = 0; i < 4; ++i) {
            const size_t a = (size_t)(m0 + wm * 64 + i * 16 + ln) * EE + ks * 32 + g * 8;
            ah[i] = *reinterpret_cast<const bf16x8*>(xhi + a);
            al[i] = *reinterpret_cast<const bf16x8*>(xlo + a);
        }
        #pragma unroll
        for (int j = 0; j < 4; ++j) {
            const size_t a = (size_t)(c0g + wc * 64 + j * 16 + ln) * EE + ks * 32 + g * 8;
            bh[j] = *reinterpret_cast<const bf16x8*>(wchi + a);
            bl[j] = *reinterpret_cast<const bf16x8*>(wclo + a);
        }
        if (wsel < 2) {
            #pragma unroll
            for (int j = 0; j < 4; ++j)
                #pragma unroll
                for (int i = 0; i < 4; ++i) {
                    acc[j][i] = __builtin_amdgcn_mfma_f32_16x16x32_bf16(bh[j], al[i], acc[j][i], 0, 0, 0);
                    acc[j][i] = __builtin_amdgcn_mfma_f32_16x16x32_bf16(bl[j], ah[i], acc[j][i], 0, 0, 0);
                    acc[j][i] = __builtin_amdgcn_mfma_f32_16x16x32_bf16(bh[j], ah[i], acc[j][i], 0, 0, 0);
                }
        } else {
            #pragma unroll
            for (int i = 0; i < 4; ++i)
                #pragma unroll
                for (int j = 0; j < 4; ++j) {
                    acc[i][j] = __builtin_amdgcn_mfma_f32_16x16x32_bf16(ah[i], bl[j], acc[i][j], 0, 0, 0);
                    acc[i][j] = __builtin_amdgcn_mfma_f32_16x16x32_bf16(al[i], bh[j], acc[i][j], 0, 0, 0);
                    acc[i][j] = __builtin_amdgcn_mfma_f32_16x16x32_bf16(ah[i], bh[j], acc[i][j], 0, 0, 0);
                }
        }
    }

    const int b  = m0 >> 9;
    const int h  = cc0 >> 7;
    const int bh_ = b * HH + h;
    const int nb = (m0 & (NN - 1));

    if (wsel < 2) {
        unsigned short* __restrict__ hp = (wsel == 0) ? Qhi : Khi;
        unsigned short* __restrict__ lp = (wsel == 0) ? Qlo : Klo;
        #pragma unroll
        for (int j = 0; j < 4; ++j) {
            const int e0 = wc * 64 + j * 16 + g * 4;
            const float4 b4 = *reinterpret_cast<const float4*>(bias + cc0 + e0);
            const float bb4[4] = {b4.x, b4.y, b4.z, b4.w};
            #pragma unroll
            for (int i = 0; i < 4; ++i) {
                const int n = nb + wm * 64 + i * 16 + ln;
                unsigned short th[4], tl[4];
                #pragma unroll
                for (int r = 0; r < 4; ++r) split2(acc[j][i][r] + bb4[r], th[r], tl[r]);
                const size_t o = ((size_t)bh_ * NN + n) * EE + e0;
                *reinterpret_cast<ushort4*>(hp + o) = *reinterpret_cast<ushort4*>(th);
                *reinterpret_cast<ushort4*>(lp + o) = *reinterpret_cast<ushort4*>(tl);
            }
        }
    } else {
        #pragma unroll
        for (int j = 0; j < 4; ++j) {
            const int e = wc * 64 + j * 16 + ln;
            const float bj = bias[cc0 + e];
            #pragma unroll
            for (int i = 0; i < 4; ++i) {
                const int n = nb + wm * 64 + i * 16 + g * 4;
                unsigned short th[4], tl[4];
                #pragma unroll
                for (int r = 0; r < 4; ++r) split2(acc[i][j][r] + bj, th[r], tl[r]);
                const size_t o = ((size_t)bh_ * EE + e) * NN + n;
                *reinterpret_cast<ushort4*>(VThi + o) = *reinterpret_cast<ushort4*>(th);
                *reinterpret_cast<ushort4*>(VTlo + o) = *reinterpret_cast<ushort4*>(tl);
            }
        }
    }
}

// ---------------------------------------------------------------------------
// k_attn R8: R6 staged structure (global_load_lds, pre-swizzled source) with
// QBLK=64, SEPARATE P buffer (no K overlay) and pipelined staging:
//   K[kt+1] issued during PV (drained by PV-end barrier);
//   V[kt+1] issued after PV-end (drained by next QK-end barrier).
// 3 barriers/tile. PV operands swapped (verified R7): D=[e][q].
// LDS = 16K*4 (K/V hi/lo) + 16K (P) = 80 KB exactly -> 2 blocks/CU.
// ---------------------------------------------------------------------------
__global__ __launch_bounds__(256, 2) void k_attn(
    const unsigned short* __restrict__ Qhi, const unsigned short* __restrict__ Qlo,
    const unsigned short* __restrict__ Khi_g, const unsigned short* __restrict__ Klo_g,
    const unsigned short* __restrict__ VThi_g, const unsigned short* __restrict__ VTlo_g,
    const float* __restrict__ dist, const float* __restrict__ mask,
    unsigned short* __restrict__ Yhi, unsigned short* __restrict__ Ylo)
{
    __shared__ __align__(16) unsigned char smem[81920];
    unsigned short* sKhi = (unsigned short*)smem;            // [64 n][128 e] swz, 16 KB
    unsigned short* sKlo = (unsigned short*)(smem + 16384);
    unsigned short* sVhi = (unsigned short*)(smem + 32768);  // [128 e][64 n] swz, 16 KB
    unsigned short* sVlo = (unsigned short*)(smem + 49152);
    unsigned* sP = (unsigned*)(smem + 65536);                // [64 q][64 k] u32 swz, 16 KB
    float* sL = (float*)(smem + 65536);                      // reused after loop

    const int tid = threadIdx.x;
    const int w  = tid >> 6;
    const int l  = tid & 63;
    const int g  = l >> 4;
    const int ln = l & 15;
    const int b  = blockIdx.x;       // lin%8 = b%8 -> whole batch on one XCD
    const int qb = blockIdx.y;
    const int h  = blockIdx.z;
    const int q0 = qb * 64;
    const int bh = b * HH + h;
    const size_t baseQ = (size_t)bh * NN * EE;
    const size_t baseV = (size_t)bh * EE * NN;

    // wave-specialized staging (0:Khi 1:Klo 2:Vhi 3:Vlo), 16 x 1KB chunks each
    const unsigned short* __restrict__ gK = (w == 0) ? Khi_g : Klo_g;
    const unsigned short* __restrict__ gV = (w == 2) ? VThi_g : VTlo_g;
    unsigned short* sDst = (unsigned short*)(smem + w * 16384);

    #define STAGE_K(KT)                                                          \
        { const int k0_ = (KT) * 64;                                             \
          _Pragma("unroll")                                                      \
          for (int c_ = 0; c_ < 16; ++c_) {                                      \
              const int n_ = c_ * 4 + (l >> 4);                                  \
              const int cs_ = ((l & 15) * 16) ^ ((n_ & 7) << 4);                 \
              gload16(gK + baseQ + (size_t)(k0_ + n_) * EE + (cs_ >> 1),         \
                      (char*)sDst + c_ * 1024 + l * 16); } }
    #define STAGE_V(KT)                                                          \
        { const int k0_ = (KT) * 64;                                             \
          _Pragma("unroll")                                                      \
          for (int c_ = 0; c_ < 16; ++c_) {                                      \
              const int e_ = c_ * 8 + (l >> 3);                                  \
              const int cs_ = ((l & 7) * 16) ^ ((e_ & 7) << 4);                  \
              gload16(gV + baseV + (size_t)e_ * NN + k0_ + (cs_ >> 1),           \
                      (char*)sDst + c_ * 1024 + l * 16); } }

    // prologue staging for tile 0
    if (w < 2) STAGE_K(0) else STAGE_V(0);

    // Q fragments (A rows = q = w*16+ln), mask rows (output rows g*4+r)
    bf16x8 qa_hi[4], qa_lo[4];
    #pragma unroll
    for (int ks = 0; ks < 4; ++ks) {
        const size_t qoff = baseQ + (size_t)(q0 + w * 16 + ln) * EE + ks * 32 + g * 8;
        qa_hi[ks] = *reinterpret_cast<const bf16x8*>(Qhi + qoff);
        qa_lo[ks] = *reinterpret_cast<const bf16x8*>(Qlo + qoff);
    }
    float mq[4];
    #pragma unroll
    for (int r = 0; r < 4; ++r) mq[r] = mask[b * NN + q0 + w * 16 + g * 4 + r];

    float lrun[4] = {0.f, 0.f, 0.f, 0.f};
    f32x4 yacc[8];
    const f32x4 fz = {0.f, 0.f, 0.f, 0.f};
    #pragma unroll
    for (int et = 0; et < 8; ++et) yacc[et] = fz;

    __syncthreads();   // tile 0 staged

    for (int kt = 0; kt < 8; ++kt) {
        const int k0 = kt * 64;

        // ---- S = Q.K^T from LDS (V[kt] staging may still be in flight) ----
        f32x4 sacc[4];
        #pragma unroll
        for (int t = 0; t < 4; ++t) sacc[t] = fz;

        __builtin_amdgcn_s_setprio(1);
        #pragma unroll
        for (int ks = 0; ks < 4; ++ks) {
            #pragma unroll
            for (int t = 0; t < 4; ++t) {
                const int row = t * 16 + ln;
                const int off = row * 256 + (((ks * 64) + g * 16) ^ ((row & 7) << 4));
                const bf16x8 kbh = *reinterpret_cast<const bf16x8*>((char*)sKhi + off);
                const bf16x8 kbl = *reinterpret_cast<const bf16x8*>((char*)sKlo + off);
                sacc[t] = __builtin_amdgcn_mfma_f32_16x16x32_bf16(qa_hi[ks], kbh, sacc[t], 0, 0, 0);
                sacc[t] = __builtin_amdgcn_mfma_f32_16x16x32_bf16(qa_lo[ks], kbh, sacc[t], 0, 0, 0);
                sacc[t] = __builtin_amdgcn_mfma_f32_16x16x32_bf16(qa_hi[ks], kbl, sacc[t], 0, 0, 0);
            }
        }
        __builtin_amdgcn_s_setprio(0);

        // dist + k-mask for this tile (consumed after the barrier)
        float mk[4];
        #pragma unroll
        for (int t = 0; t < 4; ++t) mk[t] = mask[b * NN + k0 + t * 16 + ln];
        float dv[4][4];
        #pragma unroll
        for (int r = 0; r < 4; ++r) {
            const size_t drow = ((size_t)b * NN + q0 + w * 16 + g * 4 + r) * NN + k0;
            #pragma unroll
            for (int t = 0; t < 4; ++t) dv[t][r] = dist[drow + t * 16 + ln];
        }
        __syncthreads();   // QK done (K free); drains V[kt] for waves 2/3

        // ---- no-max softmax: p = exp(s); split-packed P to LDS ----
        #pragma unroll
        for (int r = 0; r < 4; ++r) {
            float p[4], ls = 0.f;
            #pragma unroll
            for (int t = 0; t < 4; ++t) {
                const bool live = (mq[r] != 0.f) && (mk[t] != 0.f);
                const float sv = live ? fmaf(sacc[t][r], QSCALE, dv[t][r]) : NEGV;
                p[t] = __expf(sv);              // exp(-1e9) == 0 exactly
                ls += p[t];
            }
            lrun[r] += ls;
            const int q = w * 16 + g * 4 + r;
            #pragma unroll
            for (int t = 0; t < 4; ++t) {
                unsigned short ph, pl;
                split2(p[t], ph, pl);
                const int k = t * 16 + ln;
                const int off = q * 256 + ((k * 4) ^ ((q & 7) << 4));
                *reinterpret_cast<unsigned*>((char*)sP + off) = ((unsigned)ph << 16) | pl;
            }
        }
        __syncthreads();   // P visible

        // ---- issue K[kt+1] staging (K buffer free); hides under PV ----
        if (kt < 7 && w < 2) STAGE_K(kt + 1);

        // ---- Y += V.P (swapped: D rows = e, cols = q) ----
        __builtin_amdgcn_s_setprio(1);
        #pragma unroll
        for (int ks = 0; ks < 2; ++ks) {
            const int q = w * 16 + ln;
            const int swz = (q & 7) << 4;
            const int colb = ks * 128 + g * 32;
            const uint4 r0 = *reinterpret_cast<const uint4*>((char*)sP + q * 256 + (colb ^ swz));
            const uint4 r1 = *reinterpret_cast<const uint4*>((char*)sP + q * 256 + ((colb + 16) ^ swz));
            const unsigned wrd[8] = {r0.x, r0.y, r0.z, r0.w, r1.x, r1.y, r1.z, r1.w};
            unsigned hh[4], llw[4];
            #pragma unroll
            for (int d = 0; d < 4; ++d) {
                hh[d]  = __builtin_amdgcn_perm(wrd[2 * d + 1], wrd[2 * d], 0x07060302u);
                llw[d] = __builtin_amdgcn_perm(wrd[2 * d + 1], wrd[2 * d], 0x05040100u);
            }
            u32x4 th = {hh[0], hh[1], hh[2], hh[3]};
            u32x4 tl = {llw[0], llw[1], llw[2], llw[3]};
            const bf16x8 pah = __builtin_bit_cast(bf16x8, th);
            const bf16x8 pal = __builtin_bit_cast(bf16x8, tl);

            #pragma unroll
            for (int et = 0; et < 8; ++et) {
                const int e = et * 16 + ln;
                const int off = e * 128 + (((ks * 64) + g * 16) ^ ((e & 7) << 4));
                const bf16x8 vbh = *reinterpret_cast<const bf16x8*>((char*)sVhi + off);
                const bf16x8 vbl = *reinterpret_cast<const bf16x8*>((char*)sVlo + off);
                yacc[et] = __builtin_amdgcn_mfma_f32_16x16x32_bf16(vbh, pal, yacc[et], 0, 0, 0);
                yacc[et] = __builtin_amdgcn_mfma_f32_16x16x32_bf16(vbl, pah, yacc[et], 0, 0, 0);
                yacc[et] = __builtin_amdgcn_mfma_f32_16x16x32_bf16(vbh, pah, yacc[et], 0, 0, 0);
            }
        }
        __builtin_amdgcn_s_setprio(0);
        __syncthreads();   // PV done (V,P free); drains K[kt+1] for waves 0/1

        // ---- issue V[kt+1] staging (V buffer free); hides under next QK ----
        if (kt < 7 && w >= 2) STAGE_V(kt + 1);
    }
    #undef STAGE_K
    #undef STAGE_V

    // ---- row-sum reduce, transpose via dead P buffer ----
    #pragma unroll
    for (int r = 0; r < 4; ++r) {
        float ls = lrun[r];
        ls += __shfl_xor(ls, 1);
        ls += __shfl_xor(ls, 2);
        ls += __shfl_xor(ls, 4);
        ls += __shfl_xor(ls, 8);
        sL[w * 16 + g * 4 + r] = ls;
    }
    __syncthreads();
    const float linv = 1.0f / fmaxf(sL[w * 16 + ln], 1e-30f);

    // ---- epilogue: D rows = e (4 consecutive), col q = ln -> ushort4 ----
    const int q = q0 + w * 16 + ln;
    #pragma unroll
    for (int et = 0; et < 8; ++et) {
        unsigned short th[4], tl[4];
        #pragma unroll
        for (int r = 0; r < 4; ++r) split2(yacc[et][r] * linv, th[r], tl[r]);
        const size_t o = ((size_t)(b * NN + q)) * HE + h * EE + et * 16 + g * 4;
        *reinterpret_cast<ushort4*>(Yhi + o) = *reinterpret_cast<ushort4*>(th);
        *reinterpret_cast<ushort4*>(Ylo + o) = *reinterpret_cast<ushort4*>(tl);
    }
}

// ---------------------------------------------------------------------------
// k_out: swapped 3-term split MFMA (D=[c][m], float4 stores). m-tile 16,
// C split in 2 -> grid (512,2) = 1024 blocks (4/CU) for latency hiding.
// ---------------------------------------------------------------------------
__global__ __launch_bounds__(256) void k_out(
    const unsigned short* __restrict__ Yhi, const unsigned short* __restrict__ Ylo,
    const unsigned short* __restrict__ wohi, const unsigned short* __restrict__ wolo,
    const float* __restrict__ bo, const float* __restrict__ mask,
    float* __restrict__ out)
{
    const int tid = threadIdx.x;
    const int w = tid >> 6, l = tid & 63, g = l >> 4, ln = l & 15;
    const int m0 = blockIdx.x * 16;
    const int cq = blockIdx.y * 64 + w * 16;   // wave's 16 cols

    f32x4 acc = {0.f, 0.f, 0.f, 0.f};

    #pragma unroll 4
    for (int ks = 0; ks < 32; ++ks) {
        const size_t a = (size_t)(m0 + ln) * HE + ks * 32 + g * 8;
        const bf16x8 ah = *reinterpret_cast<const bf16x8*>(Yhi + a);
        const bf16x8 al = *reinterpret_cast<const bf16x8*>(Ylo + a);
        const size_t bo_ = (size_t)(cq + ln) * HE + ks * 32 + g * 8;
        const bf16x8 bh = *reinterpret_cast<const bf16x8*>(wohi + bo_);
        const bf16x8 bl = *reinterpret_cast<const bf16x8*>(wolo + bo_);
        acc = __builtin_amdgcn_mfma_f32_16x16x32_bf16(bh, al, acc, 0, 0, 0);
        acc = __builtin_amdgcn_mfma_f32_16x16x32_bf16(bl, ah, acc, 0, 0, 0);
        acc = __builtin_amdgcn_mfma_f32_16x16x32_bf16(bh, ah, acc, 0, 0, 0);
    }

    const int m = m0 + ln;
    const int b = m >> 9, n = m & (NN - 1);
    const float mm = mask[b * NN + n];
    const int c0 = cq + g * 4;
    const float4 b4 = *reinterpret_cast<const float4*>(bo + c0);
    float4 o;
    o.x = (acc[0] + b4.x) * mm;
    o.y = (acc[1] + b4.y) * mm;
    o.z = (acc[2] + b4.z) * mm;
    o.w = (acc[3] + b4.w) * mm;
    *reinterpret_cast<float4*>(out + (size_t)m * EE + c0) = o;
}

// ---------------------------------------------------------------------------
extern "C" void kernel_launch(void* const* d_in, const int* in_sizes, int n_in,
                              void* d_out, int out_size, void* d_ws, size_t ws_size,
                              hipStream_t stream) {
    const float* x    = (const float*)d_in[0];
    const float* dist = (const float*)d_in[1];
    const float* mask = (const float*)d_in[2];
    const float* Wq   = (const float*)d_in[3];
    const float* bq   = (const float*)d_in[4];
    const float* Wk   = (const float*)d_in[5];
    const float* bk   = (const float*)d_in[6];
    const float* Wv   = (const float*)d_in[7];
    const float* bv   = (const float*)d_in[8];
    const float* Wo   = (const float*)d_in[9];
    const float* bo   = (const float*)d_in[10];
    float* out = (float*)d_out;

    const size_t SZ = (size_t)BB * HH * NN * EE;     // 8,388,608 elems
    if (ws_size < SZ * 16) return;                   // 134,217,728 B
    char* ws = (char*)d_ws;
    unsigned short* Qhi  = (unsigned short*)(ws);
    unsigned short* Qlo  = (unsigned short*)(ws + 1 * 16777216);
    unsigned short* Khi  = (unsigned short*)(ws + 2 * 16777216);
    unsigned short* Klo  = (unsigned short*)(ws + 3 * 16777216);
    unsigned short* VThi = (unsigned short*)(ws + 4 * 16777216);
    unsigned short* VTlo = (unsigned short*)(ws + 5 * 16777216);
    char* yreg = ws + 6 * 16777216;
    unsigned short* Yhi  = (unsigned short*)(yreg);
    unsigned short* Ylo  = (unsigned short*)(yreg + 16777216);
    unsigned short* xhi  = (unsigned short*)(yreg);
    unsigned short* xlo  = (unsigned short*)(yreg + 2097152);
    unsigned short* wchi = (unsigned short*)(yreg + 4194304);
    unsigned short* wclo = (unsigned short*)(yreg + 4980736);
    unsigned short* wohi = (unsigned short*)(ws);
    unsigned short* wolo = (unsigned short*)(ws + 262144);

    k_split<<<1408, 256, 0, stream>>>(x, Wq, Wk, Wv, xhi, xlo, wchi, wclo);
    k_qkv<<<dim3(64, 24), 256, 0, stream>>>(xhi, xlo, wchi, wclo, bq, bk, bv,
                                            Qhi, Qlo, Khi, Klo, VThi, VTlo);
    k_attn<<<dim3(BB, NN / 64, HH), 256, 0, stream>>>(Qhi, Qlo, Khi, Klo, VThi, VTlo,
                                                      dist, mask, Yhi, Ylo);
    k_split_wo<<<128, 256, 0, stream>>>(Wo, wohi, wolo);
    k_out<<<dim3(512, 2), 256, 0, stream>>>(Yhi, Ylo, wohi, wolo, bo, mask, out);
}

// Round 9
// 265.768 us; speedup vs baseline: 2.0783x; 1.2047x over previous
//
#include <hip/hip_runtime.h>
#include <math.h>

#define BB 16
#define NN 512
#define HH 8
#define EE 128
#define HE 1024
#define QSCALE 0.08838834764831845f
#define NEGV -1000000000.0f

typedef short bf16x8 __attribute__((ext_vector_type(8)));
typedef float f32x4 __attribute__((ext_vector_type(4)));
typedef unsigned u32x4 __attribute__((ext_vector_type(4)));

// round-to-nearest-even fp32 -> bf16 pair (hi + lo residual). v ~= hi + lo to ~2^-17 rel.
__device__ __forceinline__ void split2(float v, unsigned short &hi, unsigned short &lo) {
    union { float f; unsigned u; } a; a.f = v;
    const unsigned r = (a.u + 0x7FFFu + ((a.u >> 16) & 1u)) >> 16;
    hi = (unsigned short)r;
    union { unsigned u; float f; } hf; hf.u = r << 16;
    const float res = v - hf.f;
    union { float f; unsigned u; } c; c.f = res;
    const unsigned r2 = (c.u + 0x7FFFu + ((c.u >> 16) & 1u)) >> 16;
    lo = (unsigned short)r2;
}

// direct global->LDS 16B/lane (no VGPR round-trip)
__device__ __forceinline__ void gload16(const void* g, void* l) {
    __builtin_amdgcn_global_load_lds(
        (const __attribute__((address_space(1))) unsigned*)g,
        (__attribute__((address_space(3))) unsigned*)l, 16, 0, 0);
}

// ---------------------------------------------------------------------------
// k_split: x[1048576] -> xhi/xlo; Wq|Wk|Wv (3x131072) -> wchi/wclo [3072][128]
// ---------------------------------------------------------------------------
__global__ __launch_bounds__(256) void k_split(
    const float* __restrict__ x,
    const float* __restrict__ Wq, const float* __restrict__ Wk, const float* __restrict__ Wv,
    unsigned short* __restrict__ xhi, unsigned short* __restrict__ xlo,
    unsigned short* __restrict__ wchi, unsigned short* __restrict__ wclo)
{
    const int id = blockIdx.x * 256 + threadIdx.x;
    const int i4 = id * 4;
    const float* src;
    unsigned short *dh, *dl;
    int off;
    if (i4 < 1048576) { src = x; off = i4; dh = xhi + i4; dl = xlo + i4; }
    else {
        const int j = i4 - 1048576;
        const int msel = j >> 17;
        off = j & 131071;
        src = (msel == 0) ? Wq : (msel == 1) ? Wk : Wv;
        dh = wchi + j; dl = wclo + j;
    }
    const float4 v = *reinterpret_cast<const float4*>(src + off);
    unsigned short h[4], l[4];
    split2(v.x, h[0], l[0]); split2(v.y, h[1], l[1]);
    split2(v.z, h[2], l[2]); split2(v.w, h[3], l[3]);
    *reinterpret_cast<ushort4*>(dh) = *reinterpret_cast<ushort4*>(h);
    *reinterpret_cast<ushort4*>(dl) = *reinterpret_cast<ushort4*>(l);
}

// k_split_wo: Wo [128][1024] fp32 -> wohi/wolo
__global__ __launch_bounds__(256) void k_split_wo(
    const float* __restrict__ Wo,
    unsigned short* __restrict__ wohi, unsigned short* __restrict__ wolo)
{
    const int i4 = (blockIdx.x * 256 + threadIdx.x) * 4;
    const float4 v = *reinterpret_cast<const float4*>(Wo + i4);
    unsigned short h[4], l[4];
    split2(v.x, h[0], l[0]); split2(v.y, h[1], l[1]);
    split2(v.z, h[2], l[2]); split2(v.w, h[3], l[3]);
    *reinterpret_cast<ushort4*>(wohi + i4) = *reinterpret_cast<ushort4*>(h);
    *reinterpret_cast<ushort4*>(wolo + i4) = *reinterpret_cast<ushort4*>(l);
}

// ---------------------------------------------------------------------------
// k_qkv R9: same MFMA core; NEW epilogue = per-wave LDS transpose so every
// HBM store is 16B/lane with 8 consecutive lanes covering 128B contiguous.
// Wave-private 16KB u32 buffer (hi<<16|lo), XOR-swizzled; no block barriers.
// ---------------------------------------------------------------------------
__global__ __launch_bounds__(256, 2) void k_qkv(
    const unsigned short* __restrict__ xhi, const unsigned short* __restrict__ xlo,
    const unsigned short* __restrict__ wchi, const unsigned short* __restrict__ wclo,
    const float* __restrict__ bq, const float* __restrict__ bk, const float* __restrict__ bv,
    unsigned short* __restrict__ Qhi, unsigned short* __restrict__ Qlo,
    unsigned short* __restrict__ Khi, unsigned short* __restrict__ Klo,
    unsigned short* __restrict__ VThi, unsigned short* __restrict__ VTlo)
{
    __shared__ __align__(16) unsigned sT[4][4096];   // 16KB per wave, 64KB total
    const int tid = threadIdx.x;
    const int w = tid >> 6, l = tid & 63, g = l >> 4, ln = l & 15;
    const int wm = w >> 1, wc = w & 1;
    const int m0  = blockIdx.x * 128;
    const int c0g = blockIdx.y * 128;
    const int wsel = c0g >> 10;
    const int cc0  = c0g & 1023;
    const float* __restrict__ bias = (wsel == 0) ? bq : (wsel == 1) ? bk : bv;

    f32x4 acc[4][4];
    const f32x4 fz = {0.f, 0.f, 0.f, 0.f};
    #pragma unroll
    for (int i = 0; i < 4; ++i)
        #pragma unroll
        for (int j = 0; j < 4; ++j) acc[i][j] = fz;

    #pragma unroll
    for (int ks = 0; ks < 4; ++ks) {
        bf16x8 ah[4], al[4], bh[4], bl[4];
        #pragma unroll
        for (int i = 0; i < 4; ++i) {
            const size_t a = (size_t)(m0 + wm * 64 + i * 16 + ln) * EE + ks * 32 + g * 8;
            ah[i] = *reinterpret_cast<const bf16x8*>(xhi + a);
            al[i] = *reinterpret_cast<const bf16x8*>(xlo + a);
        }
        #pragma unroll
        for (int j = 0; j < 4; ++j) {
            const size_t a = (size_t)(c0g + wc * 64 + j * 16 + ln) * EE + ks * 32 + g * 8;
            bh[j] = *reinterpret_cast<const bf16x8*>(wchi + a);
            bl[j] = *reinterpret_cast<const bf16x8*>(wclo + a);
        }
        if (wsel < 2) {
            // swapped: D=[e][n]
            #pragma unroll
            for (int j = 0; j < 4; ++j)
                #pragma unroll
                for (int i = 0; i < 4; ++i) {
                    acc[j][i] = __builtin_amdgcn_mfma_f32_16x16x32_bf16(bh[j], al[i], acc[j][i], 0, 0, 0);
                    acc[j][i] = __builtin_amdgcn_mfma_f32_16x16x32_bf16(bl[j], ah[i], acc[j][i], 0, 0, 0);
                    acc[j][i] = __builtin_amdgcn_mfma_f32_16x16x32_bf16(bh[j], ah[i], acc[j][i], 0, 0, 0);
                }
        } else {
            // D=[n][e]
            #pragma unroll
            for (int i = 0; i < 4; ++i)
                #pragma unroll
                for (int j = 0; j < 4; ++j) {
                    acc[i][j] = __builtin_amdgcn_mfma_f32_16x16x32_bf16(ah[i], bl[j], acc[i][j], 0, 0, 0);
                    acc[i][j] = __builtin_amdgcn_mfma_f32_16x16x32_bf16(al[i], bh[j], acc[i][j], 0, 0, 0);
                    acc[i][j] = __builtin_amdgcn_mfma_f32_16x16x32_bf16(ah[i], bh[j], acc[i][j], 0, 0, 0);
                }
        }
    }

    const int b  = m0 >> 9;
    const int h  = cc0 >> 7;
    const int bh_ = b * HH + h;
    const int nb = (m0 & (NN - 1));
    unsigned* tb = sT[w];

    if (wsel < 2) {
        unsigned short* __restrict__ hp = (wsel == 0) ? Qhi : Khi;
        unsigned short* __restrict__ lp = (wsel == 0) ? Qlo : Klo;
        // pack into LDS [n64][e64] (swz): lane holds e64=j*16+g*4+r, n64=i*16+ln
        #pragma unroll
        for (int j = 0; j < 4; ++j) {
            const int e0 = wc * 64 + j * 16 + g * 4;
            const float4 b4 = *reinterpret_cast<const float4*>(bias + cc0 + e0);
            const float bb4[4] = {b4.x, b4.y, b4.z, b4.w};
            #pragma unroll
            for (int i = 0; i < 4; ++i) {
                const int n64 = i * 16 + ln;
                #pragma unroll
                for (int r = 0; r < 4; ++r) {
                    const int e64 = j * 16 + g * 4 + r;
                    unsigned short th, tl;
                    split2(acc[j][i][r] + bb4[r], th, tl);
                    const int byte = n64 * 256 + ((e64 * 4) ^ ((n64 & 7) << 4));
                    *reinterpret_cast<unsigned*>((char*)tb + byte) = ((unsigned)th << 16) | tl;
                }
            }
        }
        // read back + coalesced stores: 8 lanes cover one row's 128B half
        #pragma unroll
        for (int it = 0; it < 8; ++it) {
            const int n64 = it * 8 + (l >> 3);
            const int c = l & 7;
            const int swz = (n64 & 7) << 4;
            const uint4 q0 = *reinterpret_cast<const uint4*>((char*)tb + n64 * 256 + ((c * 32) ^ swz));
            const uint4 q1 = *reinterpret_cast<const uint4*>((char*)tb + n64 * 256 + ((c * 32 + 16) ^ swz));
            const unsigned wrd[8] = {q0.x, q0.y, q0.z, q0.w, q1.x, q1.y, q1.z, q1.w};
            unsigned hh[4], llw[4];
            #pragma unroll
            for (int d = 0; d < 4; ++d) {
                hh[d]  = __builtin_amdgcn_perm(wrd[2 * d + 1], wrd[2 * d], 0x07060302u);
                llw[d] = __builtin_amdgcn_perm(wrd[2 * d + 1], wrd[2 * d], 0x05040100u);
            }
            u32x4 th = {hh[0], hh[1], hh[2], hh[3]};
            u32x4 tl = {llw[0], llw[1], llw[2], llw[3]};
            const size_t o = ((size_t)bh_ * NN + nb + wm * 64 + n64) * EE + wc * 64 + c * 8;
            *reinterpret_cast<u32x4*>(hp + o) = th;
            *reinterpret_cast<u32x4*>(lp + o) = tl;
        }
    } else {
        // pack into LDS [e64][n64] (swz): lane holds n64=i*16+g*4+r, e64=j*16+ln
        #pragma unroll
        for (int j = 0; j < 4; ++j) {
            const int e64 = j * 16 + ln;
            const float bj = bias[cc0 + wc * 64 + e64];
            #pragma unroll
            for (int i = 0; i < 4; ++i) {
                #pragma unroll
                for (int r = 0; r < 4; ++r) {
                    const int n64 = i * 16 + g * 4 + r;
                    unsigned short th, tl;
                    split2(acc[i][j][r] + bj, th, tl);
                    const int byte = e64 * 256 + ((n64 * 4) ^ ((e64 & 7) << 4));
                    *reinterpret_cast<unsigned*>((char*)tb + byte) = ((unsigned)th << 16) | tl;
                }
            }
        }
        // read back + coalesced stores along n (8 lanes = 128B of one e-row)
        #pragma unroll
        for (int it = 0; it < 8; ++it) {
            const int e64 = it * 8 + (l >> 3);
            const int c = l & 7;
            const int swz = (e64 & 7) << 4;
            const uint4 q0 = *reinterpret_cast<const uint4*>((char*)tb + e64 * 256 + ((c * 32) ^ swz));
            const uint4 q1 = *reinterpret_cast<const uint4*>((char*)tb + e64 * 256 + ((c * 32 + 16) ^ swz));
            const unsigned wrd[8] = {q0.x, q0.y, q0.z, q0.w, q1.x, q1.y, q1.z, q1.w};
            unsigned hh[4], llw[4];
            #pragma unroll
            for (int d = 0; d < 4; ++d) {
                hh[d]  = __builtin_amdgcn_perm(wrd[2 * d + 1], wrd[2 * d], 0x07060302u);
                llw[d] = __builtin_amdgcn_perm(wrd[2 * d + 1], wrd[2 * d], 0x05040100u);
            }
            u32x4 th = {hh[0], hh[1], hh[2], hh[3]};
            u32x4 tl = {llw[0], llw[1], llw[2], llw[3]};
            const size_t o = ((size_t)bh_ * EE + wc * 64 + e64) * NN + nb + wm * 64 + c * 8;
            *reinterpret_cast<u32x4*>(VThi + o) = th;
            *reinterpret_cast<u32x4*>(VTlo + o) = tl;
        }
    }
}

// ---------------------------------------------------------------------------
// k_attn R8 (unchanged): staged global_load_lds + pipelined K/V prefetch,
// separate P buffer, swapped PV, no-max softmax. 80 KB LDS, 2 blocks/CU.
// ---------------------------------------------------------------------------
__global__ __launch_bounds__(256, 2) void k_attn(
    const unsigned short* __restrict__ Qhi, const unsigned short* __restrict__ Qlo,
    const unsigned short* __restrict__ Khi_g, const unsigned short* __restrict__ Klo_g,
    const unsigned short* __restrict__ VThi_g, const unsigned short* __restrict__ VTlo_g,
    const float* __restrict__ dist, const float* __restrict__ mask,
    unsigned short* __restrict__ Yhi, unsigned short* __restrict__ Ylo)
{
    __shared__ __align__(16) unsigned char smem[81920];
    unsigned short* sKhi = (unsigned short*)smem;
    unsigned short* sKlo = (unsigned short*)(smem + 16384);
    unsigned short* sVhi = (unsigned short*)(smem + 32768);
    unsigned short* sVlo = (unsigned short*)(smem + 49152);
    unsigned* sP = (unsigned*)(smem + 65536);
    float* sL = (float*)(smem + 65536);

    const int tid = threadIdx.x;
    const int w  = tid >> 6;
    const int l  = tid & 63;
    const int g  = l >> 4;
    const int ln = l & 15;
    const int b  = blockIdx.x;
    const int qb = blockIdx.y;
    const int h  = blockIdx.z;
    const int q0 = qb * 64;
    const int bh = b * HH + h;
    const size_t baseQ = (size_t)bh * NN * EE;
    const size_t baseV = (size_t)bh * EE * NN;

    const unsigned short* __restrict__ gK = (w == 0) ? Khi_g : Klo_g;
    const unsigned short* __restrict__ gV = (w == 2) ? VThi_g : VTlo_g;
    unsigned short* sDst = (unsigned short*)(smem + w * 16384);

    #define STAGE_K(KT)                                                          \
        { const int k0_ = (KT) * 64;                                             \
          _Pragma("unroll")                                                      \
          for (int c_ = 0; c_ < 16; ++c_) {                                      \
              const int n_ = c_ * 4 + (l >> 4);                                  \
              const int cs_ = ((l & 15) * 16) ^ ((n_ & 7) << 4);                 \
              gload16(gK + baseQ + (size_t)(k0_ + n_) * EE + (cs_ >> 1),         \
                      (char*)sDst + c_ * 1024 + l * 16); } }
    #define STAGE_V(KT)                                                          \
        { const int k0_ = (KT) * 64;                                             \
          _Pragma("unroll")                                                      \
          for (int c_ = 0; c_ < 16; ++c_) {                                      \
              const int e_ = c_ * 8 + (l >> 3);                                  \
              const int cs_ = ((l & 7) * 16) ^ ((e_ & 7) << 4);                  \
              gload16(gV + baseV + (size_t)e_ * NN + k0_ + (cs_ >> 1),           \
                      (char*)sDst + c_ * 1024 + l * 16); } }

    if (w < 2) STAGE_K(0) else STAGE_V(0);

    bf16x8 qa_hi[4], qa_lo[4];
    #pragma unroll
    for (int ks = 0; ks < 4; ++ks) {
        const size_t qoff = baseQ + (size_t)(q0 + w * 16 + ln) * EE + ks * 32 + g * 8;
        qa_hi[ks] = *reinterpret_cast<const bf16x8*>(Qhi + qoff);
        qa_lo[ks] = *reinterpret_cast<const bf16x8*>(Qlo + qoff);
    }
    float mq[4];
    #pragma unroll
    for (int r = 0; r < 4; ++r) mq[r] = mask[b * NN + q0 + w * 16 + g * 4 + r];

    float lrun[4] = {0.f, 0.f, 0.f, 0.f};
    f32x4 yacc[8];
    const f32x4 fz = {0.f, 0.f, 0.f, 0.f};
    #pragma unroll
    for (int et = 0; et < 8; ++et) yacc[et] = fz;

    __syncthreads();

    for (int kt = 0; kt < 8; ++kt) {
        const int k0 = kt * 64;

        f32x4 sacc[4];
        #pragma unroll
        for (int t = 0; t < 4; ++t) sacc[t] = fz;

        __builtin_amdgcn_s_setprio(1);
        #pragma unroll
        for (int ks = 0; ks < 4; ++ks) {
            #pragma unroll
            for (int t = 0; t < 4; ++t) {
                const int row = t * 16 + ln;
                const int off = row * 256 + (((ks * 64) + g * 16) ^ ((row & 7) << 4));
                const bf16x8 kbh = *reinterpret_cast<const bf16x8*>((char*)sKhi + off);
                const bf16x8 kbl = *reinterpret_cast<const bf16x8*>((char*)sKlo + off);
                sacc[t] = __builtin_amdgcn_mfma_f32_16x16x32_bf16(qa_hi[ks], kbh, sacc[t], 0, 0, 0);
                sacc[t] = __builtin_amdgcn_mfma_f32_16x16x32_bf16(qa_lo[ks], kbh, sacc[t], 0, 0, 0);
                sacc[t] = __builtin_amdgcn_mfma_f32_16x16x32_bf16(qa_hi[ks], kbl, sacc[t], 0, 0, 0);
            }
        }
        __builtin_amdgcn_s_setprio(0);

        float mk[4];
        #pragma unroll
        for (int t = 0; t < 4; ++t) mk[t] = mask[b * NN + k0 + t * 16 + ln];
        float dv[4][4];
        #pragma unroll
        for (int r = 0; r < 4; ++r) {
            const size_t drow = ((size_t)b * NN + q0 + w * 16 + g * 4 + r) * NN + k0;
            #pragma unroll
            for (int t = 0; t < 4; ++t) dv[t][r] = dist[drow + t * 16 + ln];
        }
        __syncthreads();

        #pragma unroll
        for (int r = 0; r < 4; ++r) {
            float p[4], ls = 0.f;
            #pragma unroll
            for (int t = 0; t < 4; ++t) {
                const bool live = (mq[r] != 0.f) && (mk[t] != 0.f);
                const float sv = live ? fmaf(sacc[t][r], QSCALE, dv[t][r]) : NEGV;
                p[t] = __expf(sv);
                ls += p[t];
            }
            lrun[r] += ls;
            const int q = w * 16 + g * 4 + r;
            #pragma unroll
            for (int t = 0; t < 4; ++t) {
                unsigned short ph, pl;
                split2(p[t], ph, pl);
                const int k = t * 16 + ln;
                const int off = q * 256 + ((k * 4) ^ ((q & 7) << 4));
                *reinterpret_cast<unsigned*>((char*)sP + off) = ((unsigned)ph << 16) | pl;
            }
        }
        __syncthreads();

        if (kt < 7 && w < 2) STAGE_K(kt + 1);

        __builtin_amdgcn_s_setprio(1);
        #pragma unroll
        for (int ks = 0; ks < 2; ++ks) {
            const int q = w * 16 + ln;
            const int swz = (q & 7) << 4;
            const int colb = ks * 128 + g * 32;
            const uint4 r0 = *reinterpret_cast<const uint4*>((char*)sP + q * 256 + (colb ^ swz));
            const uint4 r1 = *reinterpret_cast<const uint4*>((char*)sP + q * 256 + ((colb + 16) ^ swz));
            const unsigned wrd[8] = {r0.x, r0.y, r0.z, r0.w, r1.x, r1.y, r1.z, r1.w};
            unsigned hh[4], llw[4];
            #pragma unroll
            for (int d = 0; d < 4; ++d) {
                hh[d]  = __builtin_amdgcn_perm(wrd[2 * d + 1], wrd[2 * d], 0x07060302u);
                llw[d] = __builtin_amdgcn_perm(wrd[2 * d + 1], wrd[2 * d], 0x05040100u);
            }
            u32x4 th = {hh[0], hh[1], hh[2], hh[3]};
            u32x4 tl = {llw[0], llw[1], llw[2], llw[3]};
            const bf16x8 pah = __builtin_bit_cast(bf16x8, th);
            const bf16x8 pal = __builtin_bit_cast(bf16x8, tl);

            #pragma unroll
            for (int et = 0; et < 8; ++et) {
                const int e = et * 16 + ln;
                const int off = e * 128 + (((ks * 64) + g * 16) ^ ((e & 7) << 4));
                const bf16x8 vbh = *reinterpret_cast<const bf16x8*>((char*)sVhi + off);
                const bf16x8 vbl = *reinterpret_cast<const bf16x8*>((char*)sVlo + off);
                yacc[et] = __builtin_amdgcn_mfma_f32_16x16x32_bf16(vbh, pal, yacc[et], 0, 0, 0);
                yacc[et] = __builtin_amdgcn_mfma_f32_16x16x32_bf16(vbl, pah, yacc[et], 0, 0, 0);
                yacc[et] = __builtin_amdgcn_mfma_f32_16x16x32_bf16(vbh, pah, yacc[et], 0, 0, 0);
            }
        }
        __builtin_amdgcn_s_setprio(0);
        __syncthreads();

        if (kt < 7 && w >= 2) STAGE_V(kt + 1);
    }
    #undef STAGE_K
    #undef STAGE_V

    #pragma unroll
    for (int r = 0; r < 4; ++r) {
        float ls = lrun[r];
        ls += __shfl_xor(ls, 1);
        ls += __shfl_xor(ls, 2);
        ls += __shfl_xor(ls, 4);
        ls += __shfl_xor(ls, 8);
        sL[w * 16 + g * 4 + r] = ls;
    }
    __syncthreads();
    const float linv = 1.0f / fmaxf(sL[w * 16 + ln], 1e-30f);

    const int q = q0 + w * 16 + ln;
    #pragma unroll
    for (int et = 0; et < 8; ++et) {
        unsigned short th[4], tl[4];
        #pragma unroll
        for (int r = 0; r < 4; ++r) split2(yacc[et][r] * linv, th[r], tl[r]);
        const size_t o = ((size_t)(b * NN + q)) * HE + h * EE + et * 16 + g * 4;
        *reinterpret_cast<ushort4*>(Yhi + o) = *reinterpret_cast<ushort4*>(th);
        *reinterpret_cast<ushort4*>(Ylo + o) = *reinterpret_cast<ushort4*>(tl);
    }
}

// ---------------------------------------------------------------------------
// k_out (unchanged): swapped 3-term split MFMA (D=[c][m], float4 stores).
// ---------------------------------------------------------------------------
__global__ __launch_bounds__(256) void k_out(
    const unsigned short* __restrict__ Yhi, const unsigned short* __restrict__ Ylo,
    const unsigned short* __restrict__ wohi, const unsigned short* __restrict__ wolo,
    const float* __restrict__ bo, const float* __restrict__ mask,
    float* __restrict__ out)
{
    const int tid = threadIdx.x;
    const int w = tid >> 6, l = tid & 63, g = l >> 4, ln = l & 15;
    const int m0 = blockIdx.x * 16;
    const int cq = blockIdx.y * 64 + w * 16;

    f32x4 acc = {0.f, 0.f, 0.f, 0.f};

    #pragma unroll 4
    for (int ks = 0; ks < 32; ++ks) {
        const size_t a = (size_t)(m0 + ln) * HE + ks * 32 + g * 8;
        const bf16x8 ah = *reinterpret_cast<const bf16x8*>(Yhi + a);
        const bf16x8 al = *reinterpret_cast<const bf16x8*>(Ylo + a);
        const size_t bo_ = (size_t)(cq + ln) * HE + ks * 32 + g * 8;
        const bf16x8 bh = *reinterpret_cast<const bf16x8*>(wohi + bo_);
        const bf16x8 bl = *reinterpret_cast<const bf16x8*>(wolo + bo_);
        acc = __builtin_amdgcn_mfma_f32_16x16x32_bf16(bh, al, acc, 0, 0, 0);
        acc = __builtin_amdgcn_mfma_f32_16x16x32_bf16(bl, ah, acc, 0, 0, 0);
        acc = __builtin_amdgcn_mfma_f32_16x16x32_bf16(bh, ah, acc, 0, 0, 0);
    }

    const int m = m0 + ln;
    const int b = m >> 9, n = m & (NN - 1);
    const float mm = mask[b * NN + n];
    const int c0 = cq + g * 4;
    const float4 b4 = *reinterpret_cast<const float4*>(bo + c0);
    float4 o;
    o.x = (acc[0] + b4.x) * mm;
    o.y = (acc[1] + b4.y) * mm;
    o.z = (acc[2] + b4.z) * mm;
    o.w = (acc[3] + b4.w) * mm;
    *reinterpret_cast<float4*>(out + (size_t)m * EE + c0) = o;
}

// ---------------------------------------------------------------------------
extern "C" void kernel_launch(void* const* d_in, const int* in_sizes, int n_in,
                              void* d_out, int out_size, void* d_ws, size_t ws_size,
                              hipStream_t stream) {
    const float* x    = (const float*)d_in[0];
    const float* dist = (const float*)d_in[1];
    const float* mask = (const float*)d_in[2];
    const float* Wq   = (const float*)d_in[3];
    const float* bq   = (const float*)d_in[4];
    const float* Wk   = (const float*)d_in[5];
    const float* bk   = (const float*)d_in[6];
    const float* Wv   = (const float*)d_in[7];
    const float* bv   = (const float*)d_in[8];
    const float* Wo   = (const float*)d_in[9];
    const float* bo   = (const float*)d_in[10];
    float* out = (float*)d_out;

    const size_t SZ = (size_t)BB * HH * NN * EE;     // 8,388,608 elems
    if (ws_size < SZ * 16) return;                   // 134,217,728 B
    char* ws = (char*)d_ws;
    unsigned short* Qhi  = (unsigned short*)(ws);
    unsigned short* Qlo  = (unsigned short*)(ws + 1 * 16777216);
    unsigned short* Khi  = (unsigned short*)(ws + 2 * 16777216);
    unsigned short* Klo  = (unsigned short*)(ws + 3 * 16777216);
    unsigned short* VThi = (unsigned short*)(ws + 4 * 16777216);
    unsigned short* VTlo = (unsigned short*)(ws + 5 * 16777216);
    char* yreg = ws + 6 * 16777216;
    unsigned short* Yhi  = (unsigned short*)(yreg);
    unsigned short* Ylo  = (unsigned short*)(yreg + 16777216);
    unsigned short* xhi  = (unsigned short*)(yreg);
    unsigned short* xlo  = (unsigned short*)(yreg + 2097152);
    unsigned short* wchi = (unsigned short*)(yreg + 4194304);
    unsigned short* wclo = (unsigned short*)(yreg + 4980736);
    unsigned short* wohi = (unsigned short*)(ws);
    unsigned short* wolo = (unsigned short*)(ws + 262144);

    k_split<<<1408, 256, 0, stream>>>(x, Wq, Wk, Wv, xhi, xlo, wchi, wclo);
    k_qkv<<<dim3(64, 24), 256, 0, stream>>>(xhi, xlo, wchi, wclo, bq, bk, bv,
                                            Qhi, Qlo, Khi, Klo, VThi, VTlo);
    k_attn<<<dim3(BB, NN / 64, HH), 256, 0, stream>>>(Qhi, Qlo, Khi, Klo, VThi, VTlo,
                                                      dist, mask, Yhi, Ylo);
    k_split_wo<<<128, 256, 0, stream>>>(Wo, wohi, wolo);
    k_out<<<dim3(512, 2), 256, 0, stream>>>(Yhi, Ylo, wohi, wolo, bo, mask, out);
}